// Round 3
// baseline (10076.472 us; speedup 1.0000x reference)
//
#include <hip/hip_runtime.h>
#include <math.h>

// ---------------- constants ----------------
// B=4 N=1024 V=20000 D=512 H=8 DH=64 W=512 NB=2 NS=512 FF=2048

// ---------------- embed ----------------
__global__ void k_embed(const int* __restrict__ x, const float* __restrict__ emb,
                        float* __restrict__ h, int total4){
  int idx = blockIdx.x*blockDim.x + threadIdx.x;
  if (idx >= total4) return;
  int row = idx >> 7;          // 128 float4 per 512-float row
  int c4  = idx & 127;
  int tok = x[row];
  reinterpret_cast<float4*>(h)[idx] =
      reinterpret_cast<const float4*>(emb)[(size_t)tok*128 + c4];
}

// ---------------- pos-bias MLP table [W,H] ----------------
__global__ void k_postable(const float* __restrict__ w1, const float* __restrict__ b1,
                           const float* __restrict__ w2, const float* __restrict__ b2,
                           const float* __restrict__ w3, const float* __restrict__ b3,
                           float* __restrict__ table){
  __shared__ float h1[128];
  __shared__ float h2[128];
  int d = blockIdx.x, t = threadIdx.x;   // 128 threads
  float a = (float)d * w1[t] + b1[t];
  h1[t] = a / (1.f + __expf(-a));        // silu
  __syncthreads();
  float acc = b2[t];
  for (int p=0;p<128;p++) acc += h1[p]*w2[p*128+t];
  h2[t] = acc / (1.f + __expf(-acc));
  __syncthreads();
  if (t < 8){
    float acc2 = b3[t];
    for (int p=0;p<128;p++) acc2 += h2[p]*w3[p*8+t];
    table[d*8+t] = acc2;
  }
}

// ---------------- layernorm (one 512-col row per block of 256) ----------------
__global__ void k_ln(const float* __restrict__ x, const float* __restrict__ g,
                     float* __restrict__ y){
  int row = blockIdx.x;
  int t = threadIdx.x;
  float2 v = reinterpret_cast<const float2*>(x + (size_t)row*512)[t];
  float s = v.x+v.y, ss = v.x*v.x+v.y*v.y;
  for (int o=32;o;o>>=1){ s += __shfl_down(s,o); ss += __shfl_down(ss,o); }
  __shared__ float ls[4], lss[4];
  __shared__ float smu, srs;
  int wid = t>>6;
  if ((t&63)==0){ ls[wid]=s; lss[wid]=ss; }
  __syncthreads();
  if (t==0){
    float S=ls[0]+ls[1]+ls[2]+ls[3], SS=lss[0]+lss[1]+lss[2]+lss[3];
    float mu = S*(1.f/512.f);
    float var = SS*(1.f/512.f) - mu*mu;
    smu = mu; srs = rsqrtf(var + 1e-5f);
  }
  __syncthreads();
  float mu=smu, rs=srs;
  float2 gg = reinterpret_cast<const float2*>(g)[t];
  reinterpret_cast<float2*>(y + (size_t)row*512)[t] =
      make_float2((v.x-mu)*rs*gg.x, (v.y-mu)*rs*gg.y);
}

// ---------------- qk rmsnorm (in place), block = 512 thr = 8 waves (one head each) ----
__global__ void k_qkrms(float* __restrict__ q, float* __restrict__ k,
                        const float* __restrict__ qs, const float* __restrict__ ks){
  int row = blockIdx.x;
  int h = threadIdx.x >> 6, d = threadIdx.x & 63;
  size_t base = (size_t)row*512 + h*64 + d;
  float qv = q[base];
  float s = qv*qv;
  for (int o=32;o;o>>=1) s += __shfl_xor(s,o);
  q[base] = qv*rsqrtf(s+1e-12f)*qs[d];
  float kv = k[base];
  float s2 = kv*kv;
  for (int o=32;o;o>>=1) s2 += __shfl_xor(s2,o);
  k[base] = kv*rsqrtf(s2+1e-12f)*ks[d];
}

// ---------------- fp32 GEMM: C[M,N] (+)= A[M,K]@B[K,N] (+bias) (gelu) ----------
__device__ __forceinline__ float geluf(float x){
  float u = 0.7978845608028654f*(x + 0.044715f*x*x*x);
  return 0.5f*x*(1.f + tanhf(u));
}

template<int ACC, int EPI>
__global__ __launch_bounds__(256)
void k_gemm(const float* __restrict__ A, const float* __restrict__ Bm,
            const float* __restrict__ bias, float* __restrict__ C,
            int M, int N, int K){
  __shared__ float As[16][68];   // [k][m], padded
  __shared__ float Bs[16][64];   // [k][n]
  int t = threadIdx.x;
  int tx = t & 15, ty = t >> 4;
  int m0 = blockIdx.y*64, n0 = blockIdx.x*64;
  int ai = t>>2, ac = (t&3)*4;
  int bk = t>>4, bj = (t&15)*4;
  float acc[4][4] = {};
  for (int k0=0;k0<K;k0+=16){
    float4 a4 = *reinterpret_cast<const float4*>(A + (size_t)(m0+ai)*K + k0+ac);
    As[ac+0][ai]=a4.x; As[ac+1][ai]=a4.y; As[ac+2][ai]=a4.z; As[ac+3][ai]=a4.w;
    float4 b4 = make_float4(0.f,0.f,0.f,0.f);
    if (n0+bj < N) b4 = *reinterpret_cast<const float4*>(Bm + (size_t)(k0+bk)*N + n0+bj);
    *reinterpret_cast<float4*>(&Bs[bk][bj]) = b4;
    __syncthreads();
#pragma unroll
    for (int kk=0;kk<16;kk++){
      float4 av = *reinterpret_cast<const float4*>(&As[kk][ty*4]);
      float4 bv = *reinterpret_cast<const float4*>(&Bs[kk][tx*4]);
      acc[0][0] += av.x*bv.x; acc[0][1] += av.x*bv.y; acc[0][2] += av.x*bv.z; acc[0][3] += av.x*bv.w;
      acc[1][0] += av.y*bv.x; acc[1][1] += av.y*bv.y; acc[1][2] += av.y*bv.z; acc[1][3] += av.y*bv.w;
      acc[2][0] += av.z*bv.x; acc[2][1] += av.z*bv.y; acc[2][2] += av.z*bv.z; acc[2][3] += av.z*bv.w;
      acc[3][0] += av.w*bv.x; acc[3][1] += av.w*bv.y; acc[3][2] += av.w*bv.z; acc[3][3] += av.w*bv.w;
    }
    __syncthreads();
  }
#pragma unroll
  for (int u=0;u<4;u++){
    int row = m0 + ty*4 + u;
    float* crow = C + (size_t)row*N;
#pragma unroll
    for (int w=0;w<4;w++){
      int col = n0 + tx*4 + w;
      if (col < N){
        float val = acc[u][w];
        if (bias) val += bias[col];
        if (EPI==1) val = geluf(val);
        if (ACC) crow[col] += val; else crow[col] = val;
      }
    }
  }
}

// ---------------- generic flash attention ----------------
// 4 waves x 8 query rows per block; two key/value segments; optional windowed
// mode (scale, pos-bias table col, causal sliding-window mask, has_mem).
__global__ __launch_bounds__(256)
void k_attn(const float* __restrict__ Q, long qB,
            const float* __restrict__ K0, long k0B, int k0R, int k0C, int k0H,
            const float* __restrict__ K1, long k1B, int k1R, int k1C, int k1H,
            const float* __restrict__ V0, long v0B, int v0R, int v0C, int v0H,
            const float* __restrict__ V1, long v1B, int v1R, int v1C, int v1H,
            int n0, int n1,
            float* __restrict__ O, long oB,
            float scale, int winmode, int has_mem,
            const float* __restrict__ table){
  __shared__ float Kt[64][68];
  __shared__ float Vt[64][68];
  __shared__ float qsm[32][68];
  __shared__ float pt[4][8][64];
  __shared__ float tcol[512];
  int b = blockIdx.z, h = blockIdx.y, rt = blockIdx.x;
  int t = threadIdx.x, w = t>>6, lane = t&63;
  int i0 = rt*32 + w*8;
  int qc = h*64;
  if (winmode){
    tcol[t]     = table[t*8 + h];
    tcol[t+256] = table[(t+256)*8 + h];
  }
#pragma unroll
  for (int r=0;r<8;r++)
    qsm[w*8+r][lane] = Q[(size_t)b*qB + (size_t)(i0+r)*512 + qc + lane];
  float o[8] = {0,0,0,0,0,0,0,0};
  float m[8], l[8] = {0,0,0,0,0,0,0,0};
#pragma unroll
  for (int r=0;r<8;r++) m[r] = -1e30f;
  int kc0 = k0H? qc : k0C, kc1 = k1H? qc : k1C;
  int vc0 = v0H? qc : v0C, vc1 = v1H? qc : v1C;
  int nk = n0+n1, nt = nk>>6;
  int sj = t>>2, sc = (t&3)*16;
  for (int jt=0;jt<nt;jt++){
    int jgs = jt*64 + sj;
    const float* kp; const float* vp;
    if (jgs < n0){
      kp = K0 + (size_t)b*k0B + (size_t)jgs*k0R + kc0 + sc;
      vp = V0 + (size_t)b*v0B + (size_t)jgs*v0R + vc0 + sc;
    } else {
      int j1 = jgs - n0;
      kp = K1 + (size_t)b*k1B + (size_t)j1*k1R + kc1 + sc;
      vp = V1 + (size_t)b*v1B + (size_t)j1*v1R + vc1 + sc;
    }
#pragma unroll
    for (int u=0;u<4;u++){
      *reinterpret_cast<float4*>(&Kt[sj][sc+u*4]) = *reinterpret_cast<const float4*>(kp + u*4);
      *reinterpret_cast<float4*>(&Vt[sj][sc+u*4]) = *reinterpret_cast<const float4*>(vp + u*4);
    }
    __syncthreads();
    int jgl = jt*64 + lane;
    float s[8] = {0,0,0,0,0,0,0,0};
#pragma unroll
    for (int d4=0;d4<16;d4++){
      float4 kv = *reinterpret_cast<const float4*>(&Kt[lane][d4*4]);
#pragma unroll
      for (int r=0;r<8;r++){
        float4 qv = *reinterpret_cast<const float4*>(&qsm[w*8+r][d4*4]);
        s[r] += kv.x*qv.x + kv.y*qv.y + kv.z*qv.z + kv.w*qv.w;
      }
    }
#pragma unroll
    for (int r=0;r<8;r++){
      float sv;
      if (winmode){
        int ia = i0 + r;
        bool valid = (jgl > ia) && (jgl <= ia+512) && (has_mem || jgl >= 512);
        sv = valid ? s[r]*scale + tcol[ia+512-jgl] : -1e9f;
      } else {
        sv = s[r]*scale;
      }
      float tm = sv;
      for (int off=32;off;off>>=1) tm = fmaxf(tm, __shfl_xor(tm,off));
      float mn = fmaxf(m[r], tm);
      float corr = __expf(m[r]-mn);
      float p = (sv <= -1e8f) ? 0.f : __expf(sv - mn);
      float ps = p;
      for (int off=32;off;off>>=1) ps += __shfl_xor(ps,off);
      l[r] = l[r]*corr + ps;
      m[r] = mn;
      o[r] *= corr;
      pt[w][r][lane] = p;
    }
    __syncthreads();
    for (int jj=0;jj<64;jj++){
      float vv = Vt[jj][lane];
#pragma unroll
      for (int r=0;r<8;r++) o[r] += pt[w][r][jj]*vv;
    }
    __syncthreads();
  }
#pragma unroll
  for (int r=0;r<8;r++)
    O[(size_t)b*oB + (size_t)(i0+r)*512 + qc + lane] = o[r]/l[r];
}

// ---------------- small utility kernels ----------------
__global__ void k_copy(float* __restrict__ dst, const float* __restrict__ src, int n){
  int idx = blockIdx.x*blockDim.x + threadIdx.x;
  if (idx < n) dst[idx] = src[idx];
}
__global__ void k_gather_xb(float* __restrict__ dst, const float* __restrict__ src, int nb){
  int idx = blockIdx.x*blockDim.x + threadIdx.x;  // 1048576
  if (idx >= 1048576) return;
  int b = idx >> 18, rem = idx & 262143;
  dst[idx] = src[(size_t)b*524288 + (size_t)nb*262144 + rem];
}
__global__ void k_xlout(float* __restrict__ dk, float* __restrict__ dv,
                        const float* __restrict__ k, const float* __restrict__ v){
  int idx = blockIdx.x*blockDim.x + threadIdx.x;  // 1048576
  if (idx >= 1048576) return;
  int b = idx >> 18, rem = idx & 262143;
  size_t s = (size_t)b*524288 + 262144 + rem;     // block 1 rows
  dk[idx] = k[s]; dv[idx] = v[s];
}
__global__ void k_ema(float* __restrict__ st, const float* __restrict__ sp,
                      const float* __restrict__ beta, int n){
  int idx = blockIdx.x*blockDim.x + threadIdx.x;
  if (idx >= n) return;
  int d = idx & 511;
  float dec = 1.f/(1.f+__expf(-beta[d]));
  st[idx] = dec*st[idx] + (1.f-dec)*sp[idx];
}

// ---------------- launcher ----------------
extern "C" void kernel_launch(void* const* d_in, const int* in_sizes, int n_in,
                              void* d_out, int out_size, void* d_ws, size_t ws_size,
                              hipStream_t stream){
  // workspace high-water mark: 24,121,344 floats (~96.5 MB). If the harness
  // scratch is smaller, bail out cleanly (wrong-answer signal) instead of
  // writing out of bounds and faulting the GPU.
  if (ws_size < (size_t)24121344 * sizeof(float)) return;

  const int*   x        = (const int*)  d_in[0];
  const float* tok_emb  = (const float*)d_in[1];
  const float* pw1 = (const float*)d_in[2];
  const float* pb1 = (const float*)d_in[3];
  const float* pw2 = (const float*)d_in[4];
  const float* pb2 = (const float*)d_in[5];
  const float* pw3 = (const float*)d_in[6];
  const float* pb3 = (const float*)d_in[7];
  const float* ln_g = (const float*)d_in[8];
  const float* Wq = (const float*)d_in[9];
  const float* Wk = (const float*)d_in[10];
  const float* Wv = (const float*)d_in[11];
  const float* Wo = (const float*)d_in[12];
  const float* q_scale = (const float*)d_in[13];
  const float* k_scale = (const float*)d_in[14];
  const float* Wo_state = (const float*)d_in[15];
  const float* state_norm_g = (const float*)d_in[16];
  const float* Wq2s = (const float*)d_in[17];
  const float* Ws2q = (const float*)d_in[18];
  const float* Ws2kv = (const float*)d_in[19];
  const float* W_state_out = (const float*)d_in[20];
  const float* ema_beta = (const float*)d_in[21];
  const float* ff_g = (const float*)d_in[22];
  const float* ff_w1 = (const float*)d_in[23];
  const float* ff_b1 = (const float*)d_in[24];
  const float* ff_w2 = (const float*)d_in[25];
  const float* ff_b2 = (const float*)d_in[26];
  const float* final_g = (const float*)d_in[27];
  const float* W_logits = (const float*)d_in[28];
  const float* xl_mem_k = (const float*)d_in[29];
  const float* xl_mem_v = (const float*)d_in[30];
  const float* states_in = (const float*)d_in[31];

  float* out = (float*)d_out;
  float* out_xlk    = out + 81920000;
  float* out_xlv    = out + 84017152;
  float* out_states = out + 86114304;

  float* p = (float*)d_ws;
  float* hstate   = p; p += 2097152;
  float* xn       = p; p += 2097152;
  float* q        = p; p += 2097152;
  float* k        = p; p += 2097152;
  float* v        = p; p += 2097152;
  float* attn_out = p; p += 2097152;
  float* to_state = p; p += 2097152;
  float* ff1      = p; p += 8388608;
  float* states_cur = p; p += 1048576;
  float* table    = p; p += 4096;
  // recurrent-layer scratch aliases inside ff1 (rec runs before FF in layer 3)
  float* sn    = ff1;
  float* skv   = ff1 + 1048576;
  float* xb    = ff1 + 1310720;
  float* q2s   = ff1 + 2359296;
  float* sq    = ff1 + 3407872;
  float* satt  = ff1 + 4456448;
  float* sproj = ff1 + 5505024;

  k_embed<<<2048, 256, 0, stream>>>(x, tok_emb, hstate, 524288);
  k_postable<<<512, 128, 0, stream>>>(pw1,pb1,pw2,pb2,pw3,pb3, table);
  k_copy<<<4096, 256, 0, stream>>>(states_cur, states_in, 1048576);

  for (int l=0;l<6;l++){
    k_ln<<<4096,256,0,stream>>>(hstate, ln_g + l*512, xn);
    k_gemm<0,0><<<dim3(8,64),256,0,stream>>>(xn, Wq + (size_t)l*262144, nullptr, q, 4096,512,512);
    k_gemm<0,0><<<dim3(8,64),256,0,stream>>>(xn, Wk + (size_t)l*262144, nullptr, k, 4096,512,512);
    k_gemm<0,0><<<dim3(8,64),256,0,stream>>>(xn, Wv + (size_t)l*262144, nullptr, v, 4096,512,512);
    float scale = 0.125f;
    if (l>=3){
      k_qkrms<<<4096,512,0,stream>>>(q, k, q_scale + l*64, k_scale + l*64);
      scale = 8.f;
    }
    bool isxl = (l==4 || l==5);
    int src = (l==4)? 1 : 0;     // roll(-1): xl layer 4 -> mem[1], layer 5 -> mem[0]
    for (int nb=0;nb<2;nb++){
      const float* K0; const float* V0; long k0B;
      int has_mem;
      if (nb==0){
        if (isxl){ K0 = xl_mem_k + (size_t)src*1048576; V0 = xl_mem_v + (size_t)src*1048576;
                   k0B = 262144; has_mem = 1; }
        else     { K0 = k; V0 = v; k0B = 524288; has_mem = 0; }   // dummy (masked)
      } else {
        K0 = k; V0 = v; k0B = 524288; has_mem = 1;                // prev block = block 0
      }
      k_attn<<<dim3(16,8,4),256,0,stream>>>(
        q + nb*262144, 524288L,
        K0, k0B, 512, 0, 1,
        k + nb*262144, 524288L, 512, 0, 1,
        V0, k0B, 512, 0, 1,
        v + nb*262144, 524288L, 512, 0, 1,
        512, 512,
        attn_out + nb*262144, 524288L,
        scale, 1, has_mem, table);
    }
    k_gemm<1,0><<<dim3(8,64),256,0,stream>>>(attn_out, Wo + (size_t)l*262144, nullptr, hstate, 4096,512,512);
    if (l==3){
      for (int nb=0;nb<2;nb++){
        k_ln<<<2048,256,0,stream>>>(states_cur, state_norm_g, sn);
        k_gemm<0,0><<<dim3(2,32),256,0,stream>>>(sn, Ws2kv, nullptr, skv, 2048,128,512);
        k_gather_xb<<<4096,256,0,stream>>>(xb, xn, nb);
        k_gemm<0,0><<<dim3(8,32),256,0,stream>>>(xb, Wq2s, nullptr, q2s, 2048,512,512);
        // block tokens -> states attention (512 keys, no mask/bias)
        k_attn<<<dim3(16,8,4),256,0,stream>>>(
          q2s, 262144L,
          skv, 65536L, 128, 0, 0,
          skv, 65536L, 128, 0, 0,
          skv, 65536L, 128, 64, 0,
          skv, 65536L, 128, 64, 0,
          512, 0,
          to_state + nb*262144, 524288L,
          0.125f, 0, 0, table);
        k_gemm<0,0><<<dim3(8,32),256,0,stream>>>(sn, Ws2q, nullptr, sq, 2048,512,512);
        // states -> [states | block tokens] attention
        k_attn<<<dim3(16,8,4),256,0,stream>>>(
          sq, 262144L,
          skv, 65536L, 128, 0, 0,
          k + nb*262144, 524288L, 512, 0, 1,
          skv, 65536L, 128, 64, 0,
          v + nb*262144, 524288L, 512, 0, 1,
          512, 512,
          satt, 262144L,
          0.125f, 0, 0, table);
        k_gemm<0,0><<<dim3(8,32),256,0,stream>>>(satt, W_state_out, nullptr, sproj, 2048,512,512);
        k_ema<<<4096,256,0,stream>>>(states_cur, sproj, ema_beta, 1048576);
      }
      k_gemm<1,0><<<dim3(8,64),256,0,stream>>>(to_state, Wo_state, nullptr, hstate, 4096,512,512);
    }
    if (isxl){
      int xli = l-4;
      k_xlout<<<4096,256,0,stream>>>(out_xlk + (size_t)xli*1048576,
                                     out_xlv + (size_t)xli*1048576, k, v);
    }
    k_ln<<<4096,256,0,stream>>>(hstate, ff_g + l*512, xn);
    k_gemm<0,1><<<dim3(32,64),256,0,stream>>>(xn, ff_w1 + (size_t)l*1048576, ff_b1 + l*2048, ff1, 4096,2048,512);
    k_gemm<1,0><<<dim3(8,64),256,0,stream>>>(ff1, ff_w2 + (size_t)l*1048576, ff_b2 + l*512, hstate, 4096,512,2048);
  }
  k_ln<<<4096,256,0,stream>>>(hstate, final_g, xn);
  k_gemm<0,0><<<dim3(313,64),256,0,stream>>>(xn, W_logits, nullptr, out, 4096,20000,512);
  k_copy<<<4096, 256, 0, stream>>>(out_states, states_cur, 1048576);
}